// Round 15
// baseline (470.597 us; speedup 1.0000x reference)
//
#include <hip/hip_runtime.h>
#include <hip/hip_bf16.h>
#include <stdint.h>

typedef unsigned short u16;
typedef uint8_t u8;
typedef float f32x4 __attribute__((ext_vector_type(4)));

// round-to-nearest-even fp32 -> bf16
__device__ __forceinline__ u16 f2b(float f){
  uint32_t u = __float_as_uint(f);
  u = (u + 0x7fffu + ((u >> 16) & 1u)) >> 16;
  return (u16)u;
}
__device__ __forceinline__ float b2f(u16 u){
  return __uint_as_float(((uint32_t)u) << 16);
}
// fp32 -> fp8 e4m3fn, RNE, saturating (never emits NaN encodings)
__device__ __forceinline__ uint32_t f2e4(float f){
  uint32_t u = __float_as_uint(f);
  uint32_t s = (u >> 24) & 0x80u;
  uint32_t a = u & 0x7fffffffu;
  if (a >= 0x43e00000u) return s | 0x7eu;            // >=448: saturate
  if (a < 0x3c800000u){                              // < 2^-6: subnormal
    float v = __uint_as_float(a) * 512.0f + 12582912.0f;  // RNE int in mantissa
    return s | (__float_as_uint(v) & 7u);
  }
  uint32_t t = a - (120u << 23);
  t += 0x7ffffu + ((t >> 20) & 1u);                  // RNE
  return s | (t >> 20);
}
// fp8 e4m3 -> f32 (exact; NaN encodings decode to large finite — inputs never NaN)
__device__ __forceinline__ float e4f(uint32_t b){
  uint32_t e = (b >> 3) & 15u, m = b & 7u;
  float mag = e ? __uint_as_float(((e + 120u) << 23) | (m << 20))
               : (float)m * 0.001953125f;
  return (b & 0x80u) ? -mag : mag;
}

typedef const void __attribute__((address_space(1))) gv_t;
typedef void __attribute__((address_space(3))) sv_t;

__device__ __forceinline__ void gload16(const void* g, void* l){
  __builtin_amdgcn_global_load_lds((gv_t*)g, (sv_t*)l, 16, 0, 0);
}

// ---------------- per-batch-side active-row count + local exclusive prefix ----
__global__ __launch_bounds__(256) void cnt_scan(const int* __restrict__ pm,
    const int* __restrict__ hm, int* __restrict__ pfx, int* __restrict__ cnts)
{
  int bs = blockIdx.x;
  const int* msk = (bs < 128) ? pm + bs*512 : hm + (bs-128)*512;
  __shared__ int sA[256], sB[256], fl[512];
  int t = threadIdx.x;
  int a = (msk[2*t] != 0), b = (msk[2*t+1] != 0);
  fl[2*t] = a; fl[2*t+1] = b;
  sA[t] = a + b;
  __syncthreads();
  int* cur = sA; int* nxt = sB;
  #pragma unroll
  for (int off = 1; off < 256; off <<= 1){
    int v = cur[t] + ((t >= off) ? cur[t-off] : 0);
    nxt[t] = v;
    __syncthreads();
    int* tmp = cur; cur = nxt; nxt = tmp;
  }
  int incl = cur[t];
  int excl = incl - fl[2*t] - fl[2*t+1];
  pfx[bs*512 + 2*t]     = excl;
  pfx[bs*512 + 2*t + 1] = excl + fl[2*t];
  if (t == 255) cnts[bs] = incl;
}

// ---------------- global scan over side counts -> gpfx[257], hloc[128] --------
__global__ __launch_bounds__(256) void gscan_k(const int* __restrict__ cnts,
    int* __restrict__ gpfx, int* __restrict__ hloc)
{
  __shared__ int sA[256], sB[256];
  int t = threadIdx.x;
  int v0 = cnts[t];
  sA[t] = v0;
  __syncthreads();
  int* cur = sA; int* nxt = sB;
  #pragma unroll
  for (int off = 1; off < 256; off <<= 1){
    int v = cur[t] + ((t >= off) ? cur[t-off] : 0);
    nxt[t] = v;
    __syncthreads();
    int* tmp = cur; cur = nxt; nxt = tmp;
  }
  int incl = cur[t];
  gpfx[t] = incl - v0;
  if (t == 255) gpfx[256] = incl;
  __syncthreads();
  if (t >= 128) hloc[t - 128] = (incl - v0) - cur[127];   // gpfx[t]-gpfx[128]
}

// ---------------- compact all live rows globally (fp32 -> fp8) + rowMap ------
__global__ __launch_bounds__(256) void compact_copy(
    const float* __restrict__ prem, const float* __restrict__ hyp,
    const int* __restrict__ pm, const int* __restrict__ hm,
    const int* __restrict__ pfx, const int* __restrict__ gpfx,
    u8* __restrict__ embC8, int* __restrict__ rowMap)
{
  int blk = blockIdx.x;
  int bs = blk >> 2, qtr = blk & 3;
  const float* src = (bs < 128) ? prem + (long)bs*262144 : hyp + (long)(bs-128)*262144;
  const int*  msk = (bs < 128) ? pm + bs*512 : hm + (bs-128)*512;
  const int*  pf  = pfx + bs*512;
  long gbase = gpfx[bs];
  int t = threadIdx.x;
  for (int idx = t; idx < 128*32; idx += 256){
    int r = qtr*128 + (idx >> 5);
    if (msk[r] == 0) continue;
    int c = (idx & 31) * 16;
    int dr = pf[r];
    long g = gbase + dr;
    if ((idx & 31) == 0) rowMap[g] = bs*512 + dr;
    const float4* s4 = (const float4*)(src + (long)r*512 + c);
    float4 v0 = s4[0], v1 = s4[1], v2 = s4[2], v3 = s4[3];
    union { u8 o[16]; uint4 q; } u;
    u.o[0]=f2e4(v0.x); u.o[1]=f2e4(v0.y); u.o[2]=f2e4(v0.z); u.o[3]=f2e4(v0.w);
    u.o[4]=f2e4(v1.x); u.o[5]=f2e4(v1.y); u.o[6]=f2e4(v1.z); u.o[7]=f2e4(v1.w);
    u.o[8]=f2e4(v2.x); u.o[9]=f2e4(v2.y); u.o[10]=f2e4(v2.z); u.o[11]=f2e4(v2.w);
    u.o[12]=f2e4(v3.x); u.o[13]=f2e4(v3.y); u.o[14]=f2e4(v3.z); u.o[15]=f2e4(v3.w);
    *(uint4*)&embC8[g*512 + c] = u.q;
  }
}

// ---------------- weight transposes fp32 [R,C] -> fp8 [C,R] ----------------
__global__ void wtrans3_k(const float* __restrict__ W0, const float* __restrict__ W1,
                          const float* __restrict__ W2, u8* __restrict__ O0,
                          u8* __restrict__ O1, u8* __restrict__ O2){
  __shared__ float tile[32][33];
  const float* W = (blockIdx.z == 0) ? W0 : (blockIdx.z == 1 ? W1 : W2);
  u8* out        = (blockIdx.z == 0) ? O0 : (blockIdx.z == 1 ? O1 : O2);
  int c0 = blockIdx.x*32, r0 = blockIdx.y*32;
  int tx = threadIdx.x & 31, ty = threadIdx.x >> 5;
  #pragma unroll
  for (int i = 0; i < 4; ++i){
    int rr = ty + i*8;
    tile[rr][tx] = W[(long)(r0+rr)*512 + c0 + tx];
  }
  __syncthreads();
  #pragma unroll
  for (int i = 0; i < 4; ++i){
    int rr = ty + i*8;
    out[(long)(c0+rr)*512 + r0 + tx] = (u8)f2e4(tile[tx][rr]);
  }
}
__global__ void wtrans_k(const float* __restrict__ W, u8* __restrict__ out, int R, int C){
  __shared__ float tile[32][33];
  int c0 = blockIdx.x*32, r0 = blockIdx.y*32;
  int tx = threadIdx.x & 31, ty = threadIdx.x >> 5;
  #pragma unroll
  for (int i = 0; i < 4; ++i){
    int rr = ty + i*8;
    tile[rr][tx] = W[(long)(r0+rr)*C + c0 + tx];
  }
  __syncthreads();
  #pragma unroll
  for (int i = 0; i < 4; ++i){
    int rr = ty + i*8;
    out[(long)(c0+rr)*R + r0 + tx] = (u8)f2e4(tile[tx][rr]);
  }
}

// ------- per-side transpose from packed fp8 embC -> fp8 embT (raw bytes) ------
__global__ __launch_bounds__(256) void btrans2(const u8* __restrict__ in,
    const int* __restrict__ gpfx, const int* __restrict__ cnts,
    u8* __restrict__ outP, u8* __restrict__ outH)
{
  __shared__ u8 tile[64][72];
  int z = blockIdx.z;
  long sbase = (long)gpfx[z] * 512;
  int cnt = cnts[z];
  int r0 = blockIdx.y*64;
  if (r0 >= ((cnt + 63) & ~63)) return;   // beyond Keff64: cols never read
  u8* dst = (z < 128) ? outP + (long)z*262144 : outH + (long)(z-128)*262144;
  int c0 = blockIdx.x*64;
  int t = threadIdx.x;
  int rr = t >> 3, cc = (t & 7)*8;
  #pragma unroll
  for (int pass = 0; pass < 2; ++pass){
    int r = rr + pass*32;
    uint2 v = {0, 0};
    if (r0 + r < cnt) v = *(const uint2*)&in[sbase + (long)(r0+r)*512 + c0+cc];
    const u8* vv = (const u8*)&v;
    #pragma unroll
    for (int j = 0; j < 8; ++j) tile[r][cc+j] = vv[j];
  }
  __syncthreads();
  #pragma unroll
  for (int pass = 0; pass < 2; ++pass){
    int r = rr + pass*32;
    union { u8 o[8]; uint2 q2; } u;
    #pragma unroll
    for (int j = 0; j < 8; ++j) u.o[j] = tile[cc+j][r];
    *(uint2*)&dst[(long)(c0+r)*512 + r0+cc] = u.q2;
  }
}

// ================= 128x128 NT fp8 GEMM, BK=64, packed-M (R10/R12-proven) ======
template<int MODE, bool SPLIT>
__global__ __launch_bounds__(256) void gemm_p8(
    const u8* __restrict__ A0, const u8* __restrict__ AP1, const u8* __restrict__ AH1,
    const u8* __restrict__ Bt, void* __restrict__ Cout, float* __restrict__ aggOut,
    const int* __restrict__ gpfx, const int* __restrict__ rowMap, int K, int cpx)
{
  __shared__ __align__(16) u8 As[2][128*64];
  __shared__ __align__(16) u8 Bs[2][128*64];
  __shared__ float redbuf[3][128];

  int Mtot = gpfx[256]; if (Mtot > 81920) Mtot = 81920;
  const int Mp = SPLIT ? gpfx[128] : 0;
  const int p = blockIdx.x;
  const int l = (p & 7)*cpx + (p >> 3);   // XCD-chunked
  const int bx = l & 3, by = l >> 2;
  const int m0 = by*128, n0 = bx*128;
  if (m0 >= Mtot) return;
  const int t = threadIdx.x, lane = t & 63, wv = t >> 6;
  const int wm = wv >> 1, wn = wv & 1, r = lane & 15, q = lane >> 4;

  f32x4 acc[4][4] = {};
  const int nt = K >> 6;

  auto stage = [&](int buf, int kb){
    #pragma unroll
    for (int h = 0; h < 2; ++h){
      int c = t + h*256;
      int row = c >> 2, pp = c & 3;
      int ks = kb + ((pp ^ ((row >> 1) & 3)) << 4);
      int gr = m0 + row;
      const u8* sA;
      if (SPLIT && ks >= 512)
        sA = (gr < Mp ? AP1 + (long)gr*512 : AH1 + (long)(gr - Mp)*512) + (ks - 512);
      else
        sA = A0 + (long)gr*512 + ks;
      gload16(sA, &As[buf][c*16]);
      gload16(Bt + (long)(n0 + row)*K + ks, &Bs[buf][c*16]);
    }
  };

  stage(0, 0);
  __syncthreads();
  for (int it = 0; it < nt; ++it){
    const int cur = it & 1;
    if (it + 1 < nt) stage(cur ^ 1, (it + 1) << 6);
    long afL[2][4], bfL[2][4];
    #pragma unroll
    for (int s = 0; s < 2; ++s){
      const int j = s*4 + q;
      #pragma unroll
      for (int mi = 0; mi < 4; ++mi){
        int row = wm*64 + mi*16 + r;
        afL[s][mi] = *(const long*)&As[cur][row*64 + ((((j>>1) ^ ((row>>1)&3))<<4) | ((j&1)<<3))];
      }
      #pragma unroll
      for (int ni = 0; ni < 4; ++ni){
        int row = wn*64 + ni*16 + r;
        bfL[s][ni] = *(const long*)&Bs[cur][row*64 + ((((j>>1) ^ ((row>>1)&3))<<4) | ((j&1)<<3))];
      }
    }
    #pragma unroll
    for (int s = 0; s < 2; ++s)
      #pragma unroll
      for (int mi = 0; mi < 4; ++mi)
        #pragma unroll
        for (int ni = 0; ni < 4; ++ni)
          acc[mi][ni] = __builtin_amdgcn_mfma_f32_16x16x32_fp8_fp8(afL[s][mi], bfL[s][ni], acc[mi][ni], 0, 0, 0);
    __syncthreads();
  }

  if constexpr (MODE == 0){
    #pragma unroll
    for (int mi = 0; mi < 4; ++mi){
      #pragma unroll
      for (int i = 0; i < 4; ++i){
        int gr = m0 + wm*64 + mi*16 + q*4 + i;
        if (gr >= Mtot) continue;
        #pragma unroll
        for (int ni = 0; ni < 4; ++ni){
          int cc = n0 + wn*64 + ni*16 + r;
          ((u8*)Cout)[(long)gr*512 + cc] = (u8)f2e4(fmaxf(acc[mi][ni][i], 0.f));
        }
      }
    }
  } else {   // MODE 2: relu + side-keyed colsum
    for (int i = t; i < 3*128; i += 256) ((float*)redbuf)[i] = 0.f;
    __syncthreads();
    const int side0 = rowMap[m0] >> 9;
    int slr[4][4];
    #pragma unroll
    for (int mi = 0; mi < 4; ++mi)
      #pragma unroll
      for (int i = 0; i < 4; ++i){
        int gr = m0 + wm*64 + mi*16 + q*4 + i;
        slr[mi][i] = (gr < Mtot) ? ((rowMap[gr] >> 9) - side0) : -1;
      }
    #pragma unroll
    for (int ni = 0; ni < 4; ++ni){
      float va = 0.f, vb = 0.f, vc = 0.f;
      #pragma unroll
      for (int mi = 0; mi < 4; ++mi)
        #pragma unroll
        for (int i = 0; i < 4; ++i){
          int sl = slr[mi][i];
          if (sl < 0) continue;
          float rv = fmaxf(acc[mi][ni][i], 0.f);
          if (sl == 0) va += rv; else if (sl == 1) vb += rv; else vc += rv;
        }
      int cc = wn*64 + ni*16 + r;
      if (va != 0.f) atomicAdd(&redbuf[0][cc], va);
      if (vb != 0.f) atomicAdd(&redbuf[1][cc], vb);
      if (vc != 0.f) atomicAdd(&redbuf[2][cc], vc);
    }
    __syncthreads();
    if (t < 128){
      #pragma unroll
      for (int sl = 0; sl < 3; ++sl){
        int side = side0 + sl;
        float v = redbuf[sl][t];
        if (side < 256 && v != 0.f) atomicAdd(&aggOut[(long)side*512 + t + n0], v);
      }
    }
  }
}

// ======= fp8 alignment GEMM (128x128), both sides, ONE dispatch ===============
__global__ __launch_bounds__(256) void gemm_a8(
    const u8* __restrict__ P2H, const u8* __restrict__ H2P,
    const u8* __restrict__ PT8, const u8* __restrict__ HT8,
    u8* __restrict__ AP, u8* __restrict__ AH,
    const int* __restrict__ cnts, const int* __restrict__ gpfx, const int* __restrict__ hloc)
{
  __shared__ __align__(16) u8 As[2][128*64];
  __shared__ __align__(16) u8 Bs[2][128*64];
  const int p = blockIdx.x;
  const int l = (p & 7)*512 + (p >> 3);   // nwg=4096
  const int side = l >> 11;
  const int r2 = l & 2047;
  const int bx = r2 & 3, by = (r2 >> 2) & 3, bz = r2 >> 4;
  const int Mlive = side ? cnts[128 + bz] : cnts[bz];
  const int m0 = by*128, n0 = bx*128;
  if (m0 >= Mlive) return;
  const int Klive = side ? cnts[bz] : cnts[128 + bz];
  int Keff = (Klive + 63) & ~63; if (Keff < 64) Keff = 64;
  const int nt = Keff >> 6;
  const long abase = side ? (long)hloc[bz] : (long)gpfx[bz];
  const u8* A0 = (side ? H2P : P2H) + abase*512;
  const u8* Bt = (side ? PT8 : HT8) + (long)bz*262144;
  u8* Cp = (side ? AH : AP) + abase*512;
  const int t = threadIdx.x, lane = t & 63, wv = t >> 6;
  const int wm = wv >> 1, wn = wv & 1, r = lane & 15, q = lane >> 4;

  f32x4 acc[4][4] = {};

  auto stage = [&](int buf, int kb){
    #pragma unroll
    for (int h = 0; h < 2; ++h){
      int c = t + h*256;
      int row = c >> 2, pp = c & 3;
      int ks = kb + ((pp ^ ((row >> 1) & 3)) << 4);
      gload16(A0 + (long)(m0 + row)*512 + ks, &As[buf][c*16]);
      gload16(Bt + (long)(n0 + row)*512 + ks, &Bs[buf][c*16]);
    }
  };

  stage(0, 0);
  __syncthreads();
  for (int it = 0; it < nt; ++it){
    const int cur = it & 1;
    if (it + 1 < nt) stage(cur ^ 1, (it + 1) << 6);
    long afL[2][4], bfL[2][4];
    #pragma unroll
    for (int s = 0; s < 2; ++s){
      const int j = s*4 + q;
      #pragma unroll
      for (int mi = 0; mi < 4; ++mi){
        int row = wm*64 + mi*16 + r;
        afL[s][mi] = *(const long*)&As[cur][row*64 + ((((j>>1) ^ ((row>>1)&3))<<4) | ((j&1)<<3))];
      }
      #pragma unroll
      for (int ni = 0; ni < 4; ++ni){
        int row = wn*64 + ni*16 + r;
        bfL[s][ni] = *(const long*)&Bs[cur][row*64 + ((((j>>1) ^ ((row>>1)&3))<<4) | ((j&1)<<3))];
      }
    }
    #pragma unroll
    for (int s = 0; s < 2; ++s)
      #pragma unroll
      for (int mi = 0; mi < 4; ++mi)
        #pragma unroll
        for (int ni = 0; ni < 4; ++ni)
          acc[mi][ni] = __builtin_amdgcn_mfma_f32_16x16x32_fp8_fp8(afL[s][mi], bfL[s][ni], acc[mi][ni], 0, 0, 0);
    __syncthreads();
  }

  #pragma unroll
  for (int mi = 0; mi < 4; ++mi){
    #pragma unroll
    for (int i = 0; i < 4; ++i){
      int lr = m0 + wm*64 + mi*16 + q*4 + i;
      if (lr >= Mlive) continue;
      #pragma unroll
      for (int ni = 0; ni < 4; ++ni){
        int cc = n0 + wn*64 + ni*16 + r;
        Cp[(long)lr*512 + cc] = (u8)f2e4(acc[mi][ni][i]);
      }
    }
  }
}

// ======= fp8 att GEMM (128x128): att(fp8) = projP @ projH^T + sm partials =====
__global__ __launch_bounds__(256) void gemm_t8(
    const u8* __restrict__ proj8, u8* __restrict__ attOut,
    const int* __restrict__ cnts, const int* __restrict__ gpfx,
    float2* __restrict__ part)
{
  __shared__ __align__(16) u8 As[2][128*64];
  __shared__ __align__(16) u8 Bs[2][128*64];
  __shared__ float2 wred4[4];
  const int p = blockIdx.x;
  const int l = (p & 7)*256 + (p >> 3);   // nwg=2048
  const int bx = l & 3, by = (l >> 2) & 3, bz = l >> 4;
  const int cp = cnts[bz], ch = cnts[128 + bz];
  const int m0 = by*128, n0 = bx*128;
  const int t = threadIdx.x, lane = t & 63, wv = t >> 6;
  if (m0 >= cp || n0 >= ch){
    if (t == 0) part[bz*16 + by*4 + bx] = float2{-3.0e38f, 0.f};
    return;
  }
  const u8* A0 = proj8 + (long)gpfx[bz]*512;
  const u8* Bt = proj8 + (long)gpfx[128 + bz]*512;
  const int wm = wv >> 1, wn = wv & 1, r = lane & 15, q = lane >> 4;

  f32x4 acc[4][4] = {};

  auto stage = [&](int buf, int kb){
    #pragma unroll
    for (int h = 0; h < 2; ++h){
      int c = t + h*256;
      int row = c >> 2, pp = c & 3;
      int ks = kb + ((pp ^ ((row >> 1) & 3)) << 4);
      gload16(A0 + (long)(m0 + row)*512 + ks, &As[buf][c*16]);
      gload16(Bt + (long)(n0 + row)*512 + ks, &Bs[buf][c*16]);
    }
  };

  stage(0, 0);
  __syncthreads();
  for (int it = 0; it < 8; ++it){
    const int cur = it & 1;
    if (it + 1 < 8) stage(cur ^ 1, (it + 1) << 6);
    long afL[2][4], bfL[2][4];
    #pragma unroll
    for (int s = 0; s < 2; ++s){
      const int j = s*4 + q;
      #pragma unroll
      for (int mi = 0; mi < 4; ++mi){
        int row = wm*64 + mi*16 + r;
        afL[s][mi] = *(const long*)&As[cur][row*64 + ((((j>>1) ^ ((row>>1)&3))<<4) | ((j&1)<<3))];
      }
      #pragma unroll
      for (int ni = 0; ni < 4; ++ni){
        int row = wn*64 + ni*16 + r;
        bfL[s][ni] = *(const long*)&Bs[cur][row*64 + ((((j>>1) ^ ((row>>1)&3))<<4) | ((j&1)<<3))];
      }
    }
    #pragma unroll
    for (int s = 0; s < 2; ++s)
      #pragma unroll
      for (int mi = 0; mi < 4; ++mi)
        #pragma unroll
        for (int ni = 0; ni < 4; ++ni)
          acc[mi][ni] = __builtin_amdgcn_mfma_f32_16x16x32_fp8_fp8(afL[s][mi], bfL[s][ni], acc[mi][ni], 0, 0, 0);
    __syncthreads();
  }

  int hc[4];
  #pragma unroll
  for (int ni = 0; ni < 4; ++ni) hc[ni] = (n0 + wn*64 + ni*16 + r) < ch;
  float tm = -3.0e38f, ts = 0.f;
  #pragma unroll
  for (int mi = 0; mi < 4; ++mi){
    #pragma unroll
    for (int i = 0; i < 4; ++i){
      int rr = m0 + wm*64 + mi*16 + q*4 + i;
      int prm = rr < cp;
      #pragma unroll
      for (int ni = 0; ni < 4; ++ni){
        float v = acc[mi][ni][i];
        int cc = n0 + wn*64 + ni*16 + r;
        attOut[(long)bz*262144 + (long)rr*512 + cc] = (u8)f2e4(v);
        float lv = (prm && hc[ni]) ? e4f((uint32_t)(u8)f2e4(v)) : -1.0e9f;
        float nm = fmaxf(tm, lv);
        ts = ts*__expf(tm - nm) + __expf(lv - nm);
        tm = nm;
      }
    }
  }
  #pragma unroll
  for (int d = 1; d < 64; d <<= 1){
    float om = __shfl_xor(tm, d), os = __shfl_xor(ts, d);
    float nm = fmaxf(tm, om);
    ts = ts*__expf(tm - nm) + os*__expf(om - nm);
    tm = nm;
  }
  if (lane == 0) wred4[wv] = float2{tm, ts};
  __syncthreads();
  if (t == 0){
    float m = wred4[0].x, s = wred4[0].y;
    #pragma unroll
    for (int w = 1; w < 4; ++w){
      float om = wred4[w].x, os = wred4[w].y, nm = fmaxf(m, om);
      s = s*__expf(m - nm) + os*__expf(om - nm); m = nm;
    }
    part[bz*16 + by*4 + bx] = float2{m, s};
  }
}

// ---------------- softmax merge (16 partials per batch) ----------------
__global__ void sm_merge(const float2* __restrict__ part, float2* __restrict__ bms){
  int b = threadIdx.x;   // 128 threads
  float m = -3.0e38f, s = 0.f;
  for (int i = 0; i < 16; ++i){
    float2 p = part[b*16 + i];
    float nm = fmaxf(m, p.x);
    s = s*__expf(m - nm) + p.y*__expf(p.x - nm);
    m = nm;
  }
  bms[b] = float2{m, 1.0f / s};
}

// ------- fused softmax-write + transpose: fp8 att -> packed fp8 p2h AND h2p ---
__global__ __launch_bounds__(256) void sm_write_t(const u8* __restrict__ att,
    const int* __restrict__ cnts, const int* __restrict__ gpfx, const int* __restrict__ hloc,
    const float2* __restrict__ bms, u8* __restrict__ p2h, u8* __restrict__ h2p)
{
  __shared__ u8 tile[64][72];
  int b = blockIdx.z, h0 = blockIdx.x*64, p0 = blockIdx.y*64;
  int cp = cnts[b], ch = cnts[128 + b];
  int cp64 = (cp + 63) & ~63, ch64 = (ch + 63) & ~63;
  bool needP = (p0 < cp) && (h0 < ch64);
  bool needH = (h0 < ch) && (p0 < cp64);
  if (!needP && !needH) return;
  float2 ms = bms[b];
  int t = threadIdx.x;
  int rr = t >> 3, cc = (t & 7)*8;
  long base = (long)b*262144;
  long pbase = gpfx[b];
  long hbase = hloc[b];
  #pragma unroll
  for (int pass = 0; pass < 2; ++pass){
    int pr = rr + pass*32;
    uint2 v = *(const uint2*)&att[base + (long)(p0+pr)*512 + h0+cc];
    const u8* vv = (const u8*)&v;
    int pa = (p0 + pr) < cp;
    union { u8 o[8]; uint2 q2; } u;
    #pragma unroll
    for (int j = 0; j < 8; ++j){
      float x = e4f(vv[j]);
      u.o[j] = (pa && (h0+cc+j) < ch) ? (u8)f2e4(__expf(x - ms.x)*ms.y) : (u8)0;
    }
    if (pa) *(uint2*)&p2h[(pbase + p0+pr)*512 + h0+cc] = u.q2;
    #pragma unroll
    for (int j = 0; j < 8; ++j) tile[pr][cc+j] = u.o[j];
  }
  __syncthreads();
  #pragma unroll
  for (int pass = 0; pass < 2; ++pass){
    int hr = rr + pass*32;
    if (h0 + hr < ch){
      union { u8 o[8]; uint2 q2; } u;
      #pragma unroll
      for (int j = 0; j < 8; ++j) u.o[j] = tile[cc+j][hr];
      *(uint2*)&h2p[(hbase + h0+hr)*512 + p0+cc] = u.q2;
    }
  }
}

// ---------------- aggregate FF, parallelized (fp32, 3 stages) ----------------
__global__ __launch_bounds__(256) void ff1_k(const float* __restrict__ agg,
    const float* __restrict__ g0, float* __restrict__ tt)
{
  __shared__ float xs[256];
  int b = blockIdx.y, kc = blockIdx.x, t = threadIdx.x;
  int kbase = kc*256;
  {
    int kk = kbase + t;
    xs[t] = (kk < 512) ? agg[b*512 + kk] : agg[(long)(128 + b)*512 + (kk - 512)];
  }
  __syncthreads();
  float ax = 0.f, ay = 0.f;
  #pragma unroll 4
  for (int k = 0; k < 256; ++k){
    float2 g = *(const float2*)(g0 + (long)(kbase + k)*512 + 2*t);
    ax += xs[k]*g.x; ay += xs[k]*g.y;
  }
  atomicAdd(&tt[b*512 + 2*t],     ax);
  atomicAdd(&tt[b*512 + 2*t + 1], ay);
}

__global__ __launch_bounds__(256) void ff2_k(const float* __restrict__ tt,
    const float* __restrict__ g1, float* __restrict__ x2)
{
  __shared__ float xs[128];
  int b = blockIdx.y, kc = blockIdx.x, t = threadIdx.x;
  int kbase = kc*128;
  if (t < 128) xs[t] = fmaxf(tt[b*512 + kbase + t], 0.f);
  __syncthreads();
  float ax = 0.f, ay = 0.f;
  #pragma unroll 4
  for (int k = 0; k < 128; ++k){
    float2 g = *(const float2*)(g1 + (long)(kbase + k)*512 + 2*t);
    ax += xs[k]*g.x; ay += xs[k]*g.y;
  }
  atomicAdd(&x2[b*512 + 2*t],     ax);
  atomicAdd(&x2[b*512 + 2*t + 1], ay);
}

__global__ __launch_bounds__(64) void score_k(const float* __restrict__ x2,
    const float* __restrict__ sc, float* __restrict__ out)
{
  int b = blockIdx.x, t = threadIdx.x;
  float s0 = 0.f, s1 = 0.f;
  for (int k = t; k < 512; k += 64){
    float v = fmaxf(x2[b*512 + k], 0.f);
    s0 += v*sc[2*k]; s1 += v*sc[2*k + 1];
  }
  #pragma unroll
  for (int d = 1; d < 64; d <<= 1){ s0 += __shfl_xor(s0, d); s1 += __shfl_xor(s1, d); }
  if (t == 0){
    float mm = fmaxf(s0, s1);
    float e0 = __expf(s0 - mm), e1 = __expf(s1 - mm);
    float inv = 1.f / (e0 + e1);
    out[2*b]     = e0*inv;
    out[2*b + 1] = e1*inv;
  }
}

// =============================== launcher ===============================
extern "C" void kernel_launch(void* const* d_in, const int* in_sizes, int n_in,
                              void* d_out, int out_size, void* d_ws, size_t ws_size,
                              hipStream_t stream) {
  const float* premise    = (const float*)d_in[0];
  const float* hypothesis = (const float*)d_in[1];
  const int*   pm         = (const int*)d_in[2];
  const int*   hm         = (const int*)d_in[3];
  const float* w_a0       = (const float*)d_in[4];
  const float* w_a1       = (const float*)d_in[5];
  const float* w_c0       = (const float*)d_in[6];
  const float* w_c1       = (const float*)d_in[7];
  const float* w_g0       = (const float*)d_in[8];
  const float* w_g1       = (const float*)d_in[9];
  const float* w_sc       = (const float*)d_in[10];
  float* out = (float*)d_out;

  const size_t MB = 1ull << 20;
  if (ws_size < 456*MB) return;

  char* ws = (char*)d_ws;
  u8*  embC8 = (u8*)(ws + 0);           // [0,40)    live until l1
  u8*  t08   = (u8*)(ws + 40*MB);       // [40,80)   ff1->ff2 only
  u8*  ap8   = (u8*)(ws + 40*MB);       // [40,60)   packed align_p (t08 dead)
  u8*  ah8   = (u8*)(ws + 60*MB);       // [60,80)   packed align_h
  u8*  proj8 = (u8*)(ws + 80*MB);       // [80,120)  ff2->att (fp8)
  u8*  cmp8  = (u8*)(ws + 80*MB);       // [80,120)  l1->l2 (proj8 dead)
  u8*  pT8   = (u8*)(ws + 160*MB);      // [160,193) p_embT per-batch fp8
  u8*  hT8   = (u8*)(ws + 200*MB);      // [200,233) h_embT per-batch fp8
  u8*  att8  = (u8*)(ws + 288*MB);      // [288,320) att->sm_write_t (fp8)
  u8*  p2h8  = (u8*)(ws + 352*MB);      // [352,372) packed fp8
  u8*  h2p8  = (u8*)(ws + 372*MB);      // [372,392) packed fp8
  u8*  wt_a0 = (u8*)(ws + 432*MB);
  u8*  wt_a1 = (u8*)(ws + 432*MB + 256*1024);
  u8*  wt_c1 = (u8*)(ws + 432*MB + 512*1024);
  u8*  wt_c0 = (u8*)(ws + 433*MB);      // [512][1024] fp8 (512 KB)
  float* agg = (float*)(ws + 434*MB);   // [256][512]
  float* tt  = (float*)(ws + 434*MB + 512*1024);
  float* x2  = (float*)(ws + 434*MB + 768*1024);
  int*   pfx = (int*)(ws + 435*MB);
  int* rowMap= (int*)(ws + 436*MB);
  int*  gpfx = (int*)(ws + 437*MB);
  int*  hloc = (int*)(ws + 437*MB + 4096);
  int*  cnts = (int*)(ws + 437*MB + 8192);
  float2* part = (float2*)(ws + 437*MB + 12288);   // 128*16 float2
  float2* bms  = (float2*)(ws + 437*MB + 32768);

  // 1. counts + prefixes, packed fp8 compaction + rowMap
  cnt_scan<<<256, 256, 0, stream>>>(pm, hm, pfx, cnts);
  gscan_k<<<1, 256, 0, stream>>>(cnts, gpfx, hloc);
  compact_copy<<<1024, 256, 0, stream>>>(premise, hypothesis, pm, hm, pfx, gpfx, embC8, rowMap);

  // 2. weight transposes (fp8) + f32 scratch clears
  wtrans3_k<<<dim3(16,16,3), 256, 0, stream>>>(w_a0, w_a1, w_c1, wt_a0, wt_a1, wt_c1);
  wtrans_k<<<dim3(16,32), 256, 0, stream>>>(w_c0, wt_c0, 1024, 512);
  hipMemsetAsync(agg, 0, 256*512*sizeof(float), stream);
  hipMemsetAsync(tt,  0, 128*512*sizeof(float), stream);
  hipMemsetAsync(x2,  0, 128*512*sizeof(float), stream);

  // 3. attend FF on packed M (fp8, 128x128): ff1 -> t08, ff2 -> proj8 (fp8)
  gemm_p8<0,false><<<2112, 256, 0, stream>>>(embC8, nullptr, nullptr, wt_a0, t08, nullptr, gpfx, nullptr, 512, 264);
  gemm_p8<0,false><<<2112, 256, 0, stream>>>(t08, nullptr, nullptr, wt_a1, proj8, nullptr, gpfx, nullptr, 512, 264);

  // 4. per-side fp8 transposes from packed embC (zero-pad to roundup64)
  btrans2<<<dim3(8,8,256), 256, 0, stream>>>(embC8, gpfx, cnts, pT8, hT8);

  // 5. att = projP @ projH^T (fp8 in AND out) + fused masked softmax partials
  gemm_t8<<<2048, 256, 0, stream>>>(proj8, att8, cnts, gpfx, part);

  // 6. softmax merge + fused fp8 write packed p2h / h2p
  sm_merge<<<1, 128, 0, stream>>>(part, bms);
  sm_write_t<<<dim3(8,8,128), 256, 0, stream>>>(att8, cnts, gpfx, hloc, bms, p2h8, h2p8);

  // 7. both alignments in ONE fp8 dispatch (128x128)
  gemm_a8<<<4096, 256, 0, stream>>>(p2h8, h2p8, pT8, hT8, ap8, ah8, cnts, gpfx, hloc);

  // 8. compare l1 (fp8, K=1024 split concat) -> fp8 cmp_t
  gemm_p8<0,true><<<2112, 256, 0, stream>>>(embC8, ap8, ah8, wt_c0, cmp8, nullptr, gpfx, nullptr, 1024, 264);

  // 9. compare l2 (fp8) + relu + side-keyed column-sum into agg
  gemm_p8<2,false><<<2112, 256, 0, stream>>>(cmp8, nullptr, nullptr, wt_c1, nullptr, agg, gpfx, rowMap, 512, 264);

  // 10. aggregate FF (parallel fp32) + scorer + 2-class softmax
  ff1_k<<<dim3(4,128), 256, 0, stream>>>(agg, w_g0, tt);
  ff2_k<<<dim3(4,128), 256, 0, stream>>>(tt, w_g1, x2);
  score_k<<<128, 64, 0, stream>>>(x2, w_sc, out);
}

// Round 16
// 444.110 us; speedup vs baseline: 1.0596x; 1.0596x over previous
//
#include <hip/hip_runtime.h>
#include <hip/hip_bf16.h>
#include <stdint.h>

typedef unsigned short u16;
typedef uint8_t u8;
typedef float f32x4 __attribute__((ext_vector_type(4)));

// round-to-nearest-even fp32 -> bf16
__device__ __forceinline__ u16 f2b(float f){
  uint32_t u = __float_as_uint(f);
  u = (u + 0x7fffu + ((u >> 16) & 1u)) >> 16;
  return (u16)u;
}
__device__ __forceinline__ float b2f(u16 u){
  return __uint_as_float(((uint32_t)u) << 16);
}
// fp32 -> fp8 e4m3fn, RNE, saturating
__device__ __forceinline__ uint32_t f2e4(float f){
  uint32_t u = __float_as_uint(f);
  uint32_t s = (u >> 24) & 0x80u;
  uint32_t a = u & 0x7fffffffu;
  if (a >= 0x43e00000u) return s | 0x7eu;            // >=448: saturate
  if (a < 0x3c800000u){                              // < 2^-6: subnormal
    float v = __uint_as_float(a) * 512.0f + 12582912.0f;  // RNE int in mantissa
    return s | (__float_as_uint(v) & 7u);
  }
  uint32_t t = a - (120u << 23);
  t += 0x7ffffu + ((t >> 20) & 1u);                  // RNE
  return s | (t >> 20);
}

typedef const void __attribute__((address_space(1))) gv_t;
typedef void __attribute__((address_space(3))) sv_t;

__device__ __forceinline__ void gload16(const void* g, void* l){
  __builtin_amdgcn_global_load_lds((gv_t*)g, (sv_t*)l, 16, 0, 0);
}

// ---------------- per-batch-side active-row count + local exclusive prefix ----
__global__ __launch_bounds__(256) void cnt_scan(const int* __restrict__ pm,
    const int* __restrict__ hm, int* __restrict__ pfx, int* __restrict__ cnts)
{
  int bs = blockIdx.x;
  const int* msk = (bs < 128) ? pm + bs*512 : hm + (bs-128)*512;
  __shared__ int sA[256], sB[256], fl[512];
  int t = threadIdx.x;
  int a = (msk[2*t] != 0), b = (msk[2*t+1] != 0);
  fl[2*t] = a; fl[2*t+1] = b;
  sA[t] = a + b;
  __syncthreads();
  int* cur = sA; int* nxt = sB;
  #pragma unroll
  for (int off = 1; off < 256; off <<= 1){
    int v = cur[t] + ((t >= off) ? cur[t-off] : 0);
    nxt[t] = v;
    __syncthreads();
    int* tmp = cur; cur = nxt; nxt = tmp;
  }
  int incl = cur[t];
  int excl = incl - fl[2*t] - fl[2*t+1];
  pfx[bs*512 + 2*t]     = excl;
  pfx[bs*512 + 2*t + 1] = excl + fl[2*t];
  if (t == 255) cnts[bs] = incl;
}

// ---------------- global scan over side counts -> gpfx[257], hloc[128] --------
__global__ __launch_bounds__(256) void gscan_k(const int* __restrict__ cnts,
    int* __restrict__ gpfx, int* __restrict__ hloc)
{
  __shared__ int sA[256], sB[256];
  int t = threadIdx.x;
  int v0 = cnts[t];
  sA[t] = v0;
  __syncthreads();
  int* cur = sA; int* nxt = sB;
  #pragma unroll
  for (int off = 1; off < 256; off <<= 1){
    int v = cur[t] + ((t >= off) ? cur[t-off] : 0);
    nxt[t] = v;
    __syncthreads();
    int* tmp = cur; cur = nxt; nxt = tmp;
  }
  int incl = cur[t];
  gpfx[t] = incl - v0;
  if (t == 255) gpfx[256] = incl;
  __syncthreads();
  if (t >= 128) hloc[t - 128] = (incl - v0) - cur[127];   // gpfx[t]-gpfx[128]
}

// ---------------- compact all live rows globally (fp32 -> fp8) + rowMap ------
__global__ __launch_bounds__(256) void compact_copy(
    const float* __restrict__ prem, const float* __restrict__ hyp,
    const int* __restrict__ pm, const int* __restrict__ hm,
    const int* __restrict__ pfx, const int* __restrict__ gpfx,
    u8* __restrict__ embC8, int* __restrict__ rowMap)
{
  int blk = blockIdx.x;
  int bs = blk >> 2, qtr = blk & 3;
  const float* src = (bs < 128) ? prem + (long)bs*262144 : hyp + (long)(bs-128)*262144;
  const int*  msk = (bs < 128) ? pm + bs*512 : hm + (bs-128)*512;
  const int*  pf  = pfx + bs*512;
  long gbase = gpfx[bs];
  int t = threadIdx.x;
  for (int idx = t; idx < 128*32; idx += 256){
    int r = qtr*128 + (idx >> 5);
    if (msk[r] == 0) continue;
    int c = (idx & 31) * 16;
    int dr = pf[r];
    long g = gbase + dr;
    if ((idx & 31) == 0) rowMap[g] = bs*512 + dr;
    const float4* s4 = (const float4*)(src + (long)r*512 + c);
    float4 v0 = s4[0], v1 = s4[1], v2 = s4[2], v3 = s4[3];
    union { u8 o[16]; uint4 q; } u;
    u.o[0]=f2e4(v0.x); u.o[1]=f2e4(v0.y); u.o[2]=f2e4(v0.z); u.o[3]=f2e4(v0.w);
    u.o[4]=f2e4(v1.x); u.o[5]=f2e4(v1.y); u.o[6]=f2e4(v1.z); u.o[7]=f2e4(v1.w);
    u.o[8]=f2e4(v2.x); u.o[9]=f2e4(v2.y); u.o[10]=f2e4(v2.z); u.o[11]=f2e4(v2.w);
    u.o[12]=f2e4(v3.x); u.o[13]=f2e4(v3.y); u.o[14]=f2e4(v3.z); u.o[15]=f2e4(v3.w);
    *(uint4*)&embC8[g*512 + c] = u.q;
  }
}

// ---------------- weight transposes fp32 [R,C] -> fp8 [C,R] ----------------
__global__ void wtrans3_k(const float* __restrict__ W0, const float* __restrict__ W1,
                          const float* __restrict__ W2, u8* __restrict__ O0,
                          u8* __restrict__ O1, u8* __restrict__ O2){
  __shared__ float tile[32][33];
  const float* W = (blockIdx.z == 0) ? W0 : (blockIdx.z == 1 ? W1 : W2);
  u8* out        = (blockIdx.z == 0) ? O0 : (blockIdx.z == 1 ? O1 : O2);
  int c0 = blockIdx.x*32, r0 = blockIdx.y*32;
  int tx = threadIdx.x & 31, ty = threadIdx.x >> 5;
  #pragma unroll
  for (int i = 0; i < 4; ++i){
    int rr = ty + i*8;
    tile[rr][tx] = W[(long)(r0+rr)*512 + c0 + tx];
  }
  __syncthreads();
  #pragma unroll
  for (int i = 0; i < 4; ++i){
    int rr = ty + i*8;
    out[(long)(c0+rr)*512 + r0 + tx] = (u8)f2e4(tile[tx][rr]);
  }
}
__global__ void wtrans_k(const float* __restrict__ W, u8* __restrict__ out, int R, int C){
  __shared__ float tile[32][33];
  int c0 = blockIdx.x*32, r0 = blockIdx.y*32;
  int tx = threadIdx.x & 31, ty = threadIdx.x >> 5;
  #pragma unroll
  for (int i = 0; i < 4; ++i){
    int rr = ty + i*8;
    tile[rr][tx] = W[(long)(r0+rr)*C + c0 + tx];
  }
  __syncthreads();
  #pragma unroll
  for (int i = 0; i < 4; ++i){
    int rr = ty + i*8;
    out[(long)(c0+rr)*R + r0 + tx] = (u8)f2e4(tile[tx][rr]);
  }
}

// ------- per-side transpose from packed fp8 embC -> fp8 embT (raw bytes) ------
__global__ __launch_bounds__(256) void btrans2(const u8* __restrict__ in,
    const int* __restrict__ gpfx, const int* __restrict__ cnts,
    u8* __restrict__ outP, u8* __restrict__ outH)
{
  __shared__ u8 tile[64][72];
  int z = blockIdx.z;
  long sbase = (long)gpfx[z] * 512;
  int cnt = cnts[z];
  int r0 = blockIdx.y*64;
  if (r0 >= ((cnt + 63) & ~63)) return;   // beyond Keff64: cols never read
  u8* dst = (z < 128) ? outP + (long)z*262144 : outH + (long)(z-128)*262144;
  int c0 = blockIdx.x*64;
  int t = threadIdx.x;
  int rr = t >> 3, cc = (t & 7)*8;
  #pragma unroll
  for (int pass = 0; pass < 2; ++pass){
    int r = rr + pass*32;
    uint2 v = {0, 0};
    if (r0 + r < cnt) v = *(const uint2*)&in[sbase + (long)(r0+r)*512 + c0+cc];
    const u8* vv = (const u8*)&v;
    #pragma unroll
    for (int j = 0; j < 8; ++j) tile[r][cc+j] = vv[j];
  }
  __syncthreads();
  #pragma unroll
  for (int pass = 0; pass < 2; ++pass){
    int r = rr + pass*32;
    union { u8 o[8]; uint2 q2; } u;
    #pragma unroll
    for (int j = 0; j < 8; ++j) u.o[j] = tile[cc+j][r];
    *(uint2*)&dst[(long)(c0+r)*512 + r0+cc] = u.q2;
  }
}

// ================= 128x128 NT fp8 GEMM, BK=64, packed-M (R10/R12/R14-proven) ==
template<int MODE, bool SPLIT>
__global__ __launch_bounds__(256) void gemm_p8(
    const u8* __restrict__ A0, const u8* __restrict__ AP1, const u8* __restrict__ AH1,
    const u8* __restrict__ Bt, void* __restrict__ Cout, float* __restrict__ aggOut,
    const int* __restrict__ gpfx, const int* __restrict__ rowMap, int K, int cpx)
{
  __shared__ __align__(16) u8 As[2][128*64];
  __shared__ __align__(16) u8 Bs[2][128*64];
  __shared__ float redbuf[3][128];

  int Mtot = gpfx[256]; if (Mtot > 81920) Mtot = 81920;
  const int Mp = SPLIT ? gpfx[128] : 0;
  const int p = blockIdx.x;
  const int l = (p & 7)*cpx + (p >> 3);   // XCD-chunked
  const int bx = l & 3, by = l >> 2;
  const int m0 = by*128, n0 = bx*128;
  if (m0 >= Mtot) return;
  const int t = threadIdx.x, lane = t & 63, wv = t >> 6;
  const int wm = wv >> 1, wn = wv & 1, r = lane & 15, q = lane >> 4;

  f32x4 acc[4][4] = {};
  const int nt = K >> 6;

  auto stage = [&](int buf, int kb){
    #pragma unroll
    for (int h = 0; h < 2; ++h){
      int c = t + h*256;
      int row = c >> 2, pp = c & 3;
      int ks = kb + ((pp ^ ((row >> 1) & 3)) << 4);
      int gr = m0 + row;
      const u8* sA;
      if (SPLIT && ks >= 512)
        sA = (gr < Mp ? AP1 + (long)gr*512 : AH1 + (long)(gr - Mp)*512) + (ks - 512);
      else
        sA = A0 + (long)gr*512 + ks;
      gload16(sA, &As[buf][c*16]);
      gload16(Bt + (long)(n0 + row)*K + ks, &Bs[buf][c*16]);
    }
  };

  stage(0, 0);
  __syncthreads();
  for (int it = 0; it < nt; ++it){
    const int cur = it & 1;
    if (it + 1 < nt) stage(cur ^ 1, (it + 1) << 6);
    long afL[2][4], bfL[2][4];
    #pragma unroll
    for (int s = 0; s < 2; ++s){
      const int j = s*4 + q;
      #pragma unroll
      for (int mi = 0; mi < 4; ++mi){
        int row = wm*64 + mi*16 + r;
        afL[s][mi] = *(const long*)&As[cur][row*64 + ((((j>>1) ^ ((row>>1)&3))<<4) | ((j&1)<<3))];
      }
      #pragma unroll
      for (int ni = 0; ni < 4; ++ni){
        int row = wn*64 + ni*16 + r;
        bfL[s][ni] = *(const long*)&Bs[cur][row*64 + ((((j>>1) ^ ((row>>1)&3))<<4) | ((j&1)<<3))];
      }
    }
    #pragma unroll
    for (int s = 0; s < 2; ++s)
      #pragma unroll
      for (int mi = 0; mi < 4; ++mi)
        #pragma unroll
        for (int ni = 0; ni < 4; ++ni)
          acc[mi][ni] = __builtin_amdgcn_mfma_f32_16x16x32_fp8_fp8(afL[s][mi], bfL[s][ni], acc[mi][ni], 0, 0, 0);
    __syncthreads();
  }

  if constexpr (MODE == 0){
    #pragma unroll
    for (int mi = 0; mi < 4; ++mi){
      #pragma unroll
      for (int i = 0; i < 4; ++i){
        int gr = m0 + wm*64 + mi*16 + q*4 + i;
        if (gr >= Mtot) continue;
        #pragma unroll
        for (int ni = 0; ni < 4; ++ni){
          int cc = n0 + wn*64 + ni*16 + r;
          ((u8*)Cout)[(long)gr*512 + cc] = (u8)f2e4(fmaxf(acc[mi][ni][i], 0.f));
        }
      }
    }
  } else {   // MODE 2: relu + side-keyed colsum
    for (int i = t; i < 3*128; i += 256) ((float*)redbuf)[i] = 0.f;
    __syncthreads();
    const int side0 = rowMap[m0] >> 9;
    int slr[4][4];
    #pragma unroll
    for (int mi = 0; mi < 4; ++mi)
      #pragma unroll
      for (int i = 0; i < 4; ++i){
        int gr = m0 + wm*64 + mi*16 + q*4 + i;
        slr[mi][i] = (gr < Mtot) ? ((rowMap[gr] >> 9) - side0) : -1;
      }
    #pragma unroll
    for (int ni = 0; ni < 4; ++ni){
      float va = 0.f, vb = 0.f, vc = 0.f;
      #pragma unroll
      for (int mi = 0; mi < 4; ++mi)
        #pragma unroll
        for (int i = 0; i < 4; ++i){
          int sl = slr[mi][i];
          if (sl < 0) continue;
          float rv = fmaxf(acc[mi][ni][i], 0.f);
          if (sl == 0) va += rv; else if (sl == 1) vb += rv; else vc += rv;
        }
      int cc = wn*64 + ni*16 + r;
      if (va != 0.f) atomicAdd(&redbuf[0][cc], va);
      if (vb != 0.f) atomicAdd(&redbuf[1][cc], vb);
      if (vc != 0.f) atomicAdd(&redbuf[2][cc], vc);
    }
    __syncthreads();
    if (t < 128){
      #pragma unroll
      for (int sl = 0; sl < 3; ++sl){
        int side = side0 + sl;
        float v = redbuf[sl][t];
        if (side < 256 && v != 0.f) atomicAdd(&aggOut[(long)side*512 + t + n0], v);
      }
    }
  }
}

// ======= fp8 alignment GEMM (128x128), both sides, ONE dispatch ===============
__global__ __launch_bounds__(256) void gemm_a8(
    const u8* __restrict__ P2H, const u8* __restrict__ H2P,
    const u8* __restrict__ PT8, const u8* __restrict__ HT8,
    u8* __restrict__ AP, u8* __restrict__ AH,
    const int* __restrict__ cnts, const int* __restrict__ gpfx, const int* __restrict__ hloc)
{
  __shared__ __align__(16) u8 As[2][128*64];
  __shared__ __align__(16) u8 Bs[2][128*64];
  const int p = blockIdx.x;
  const int l = (p & 7)*512 + (p >> 3);   // nwg=4096
  const int side = l >> 11;
  const int r2 = l & 2047;
  const int bx = r2 & 3, by = (r2 >> 2) & 3, bz = r2 >> 4;
  const int Mlive = side ? cnts[128 + bz] : cnts[bz];
  const int m0 = by*128, n0 = bx*128;
  if (m0 >= Mlive) return;
  const int Klive = side ? cnts[bz] : cnts[128 + bz];
  int Keff = (Klive + 63) & ~63; if (Keff < 64) Keff = 64;
  const int nt = Keff >> 6;
  const long abase = side ? (long)hloc[bz] : (long)gpfx[bz];
  const u8* A0 = (side ? H2P : P2H) + abase*512;
  const u8* Bt = (side ? PT8 : HT8) + (long)bz*262144;
  u8* Cp = (side ? AH : AP) + abase*512;
  const int t = threadIdx.x, lane = t & 63, wv = t >> 6;
  const int wm = wv >> 1, wn = wv & 1, r = lane & 15, q = lane >> 4;

  f32x4 acc[4][4] = {};

  auto stage = [&](int buf, int kb){
    #pragma unroll
    for (int h = 0; h < 2; ++h){
      int c = t + h*256;
      int row = c >> 2, pp = c & 3;
      int ks = kb + ((pp ^ ((row >> 1) & 3)) << 4);
      gload16(A0 + (long)(m0 + row)*512 + ks, &As[buf][c*16]);
      gload16(Bt + (long)(n0 + row)*512 + ks, &Bs[buf][c*16]);
    }
  };

  stage(0, 0);
  __syncthreads();
  for (int it = 0; it < nt; ++it){
    const int cur = it & 1;
    if (it + 1 < nt) stage(cur ^ 1, (it + 1) << 6);
    long afL[2][4], bfL[2][4];
    #pragma unroll
    for (int s = 0; s < 2; ++s){
      const int j = s*4 + q;
      #pragma unroll
      for (int mi = 0; mi < 4; ++mi){
        int row = wm*64 + mi*16 + r;
        afL[s][mi] = *(const long*)&As[cur][row*64 + ((((j>>1) ^ ((row>>1)&3))<<4) | ((j&1)<<3))];
      }
      #pragma unroll
      for (int ni = 0; ni < 4; ++ni){
        int row = wn*64 + ni*16 + r;
        bfL[s][ni] = *(const long*)&Bs[cur][row*64 + ((((j>>1) ^ ((row>>1)&3))<<4) | ((j&1)<<3))];
      }
    }
    #pragma unroll
    for (int s = 0; s < 2; ++s)
      #pragma unroll
      for (int mi = 0; mi < 4; ++mi)
        #pragma unroll
        for (int ni = 0; ni < 4; ++ni)
          acc[mi][ni] = __builtin_amdgcn_mfma_f32_16x16x32_fp8_fp8(afL[s][mi], bfL[s][ni], acc[mi][ni], 0, 0, 0);
    __syncthreads();
  }

  #pragma unroll
  for (int mi = 0; mi < 4; ++mi){
    #pragma unroll
    for (int i = 0; i < 4; ++i){
      int lr = m0 + wm*64 + mi*16 + q*4 + i;
      if (lr >= Mlive) continue;
      #pragma unroll
      for (int ni = 0; ni < 4; ++ni){
        int cc = n0 + wn*64 + ni*16 + r;
        Cp[(long)lr*512 + cc] = (u8)f2e4(acc[mi][ni][i]);
      }
    }
  }
}

// ======= fp8 att GEMM (128x128): att(bf16) = projP @ projH^T + sm partials ====
__global__ __launch_bounds__(256) void gemm_t8(
    const u8* __restrict__ proj8, u16* __restrict__ attOut,
    const int* __restrict__ cnts, const int* __restrict__ gpfx,
    float2* __restrict__ part)
{
  __shared__ __align__(16) u8 As[2][128*64];
  __shared__ __align__(16) u8 Bs[2][128*64];
  __shared__ float2 wred4[4];
  const int p = blockIdx.x;
  const int l = (p & 7)*256 + (p >> 3);   // nwg=2048
  const int bx = l & 3, by = (l >> 2) & 3, bz = l >> 4;
  const int cp = cnts[bz], ch = cnts[128 + bz];
  const int m0 = by*128, n0 = bx*128;
  const int t = threadIdx.x, lane = t & 63, wv = t >> 6;
  if (m0 >= cp || n0 >= ch){
    if (t == 0) part[bz*16 + by*4 + bx] = float2{-3.0e38f, 0.f};
    return;
  }
  const u8* A0 = proj8 + (long)gpfx[bz]*512;
  const u8* Bt = proj8 + (long)gpfx[128 + bz]*512;
  const int wm = wv >> 1, wn = wv & 1, r = lane & 15, q = lane >> 4;

  f32x4 acc[4][4] = {};

  auto stage = [&](int buf, int kb){
    #pragma unroll
    for (int h = 0; h < 2; ++h){
      int c = t + h*256;
      int row = c >> 2, pp = c & 3;
      int ks = kb + ((pp ^ ((row >> 1) & 3)) << 4);
      gload16(A0 + (long)(m0 + row)*512 + ks, &As[buf][c*16]);
      gload16(Bt + (long)(n0 + row)*512 + ks, &Bs[buf][c*16]);
    }
  };

  stage(0, 0);
  __syncthreads();
  for (int it = 0; it < 8; ++it){
    const int cur = it & 1;
    if (it + 1 < 8) stage(cur ^ 1, (it + 1) << 6);
    long afL[2][4], bfL[2][4];
    #pragma unroll
    for (int s = 0; s < 2; ++s){
      const int j = s*4 + q;
      #pragma unroll
      for (int mi = 0; mi < 4; ++mi){
        int row = wm*64 + mi*16 + r;
        afL[s][mi] = *(const long*)&As[cur][row*64 + ((((j>>1) ^ ((row>>1)&3))<<4) | ((j&1)<<3))];
      }
      #pragma unroll
      for (int ni = 0; ni < 4; ++ni){
        int row = wn*64 + ni*16 + r;
        bfL[s][ni] = *(const long*)&Bs[cur][row*64 + ((((j>>1) ^ ((row>>1)&3))<<4) | ((j&1)<<3))];
      }
    }
    #pragma unroll
    for (int s = 0; s < 2; ++s)
      #pragma unroll
      for (int mi = 0; mi < 4; ++mi)
        #pragma unroll
        for (int ni = 0; ni < 4; ++ni)
          acc[mi][ni] = __builtin_amdgcn_mfma_f32_16x16x32_fp8_fp8(afL[s][mi], bfL[s][ni], acc[mi][ni], 0, 0, 0);
    __syncthreads();
  }

  int hc[4];
  #pragma unroll
  for (int ni = 0; ni < 4; ++ni) hc[ni] = (n0 + wn*64 + ni*16 + r) < ch;
  float tm = -3.0e38f, ts = 0.f;
  #pragma unroll
  for (int mi = 0; mi < 4; ++mi){
    #pragma unroll
    for (int i = 0; i < 4; ++i){
      int rr = m0 + wm*64 + mi*16 + q*4 + i;
      int prm = rr < cp;
      #pragma unroll
      for (int ni = 0; ni < 4; ++ni){
        float v = acc[mi][ni][i];
        int cc = n0 + wn*64 + ni*16 + r;
        attOut[(long)bz*262144 + (long)rr*512 + cc] = f2b(v);
        float lv = (prm && hc[ni]) ? v : -1.0e9f;
        float nm = fmaxf(tm, lv);
        ts = ts*__expf(tm - nm) + __expf(lv - nm);
        tm = nm;
      }
    }
  }
  #pragma unroll
  for (int d = 1; d < 64; d <<= 1){
    float om = __shfl_xor(tm, d), os = __shfl_xor(ts, d);
    float nm = fmaxf(tm, om);
    ts = ts*__expf(tm - nm) + os*__expf(om - nm);
    tm = nm;
  }
  if (lane == 0) wred4[wv] = float2{tm, ts};
  __syncthreads();
  if (t == 0){
    float m = wred4[0].x, s = wred4[0].y;
    #pragma unroll
    for (int w = 1; w < 4; ++w){
      float om = wred4[w].x, os = wred4[w].y, nm = fmaxf(m, om);
      s = s*__expf(m - nm) + os*__expf(om - nm); m = nm;
    }
    part[bz*16 + by*4 + bx] = float2{m, s};
  }
}

// ---------------- softmax merge (16 partials per batch) ----------------
__global__ void sm_merge(const float2* __restrict__ part, float2* __restrict__ bms){
  int b = threadIdx.x;   // 128 threads
  float m = -3.0e38f, s = 0.f;
  for (int i = 0; i < 16; ++i){
    float2 p = part[b*16 + i];
    float nm = fmaxf(m, p.x);
    s = s*__expf(m - nm) + p.y*__expf(p.x - nm);
    m = nm;
  }
  bms[b] = float2{m, 1.0f / s};
}

// ------- fused softmax-write + transpose: att -> packed fp8 p2h AND h2p -------
__global__ __launch_bounds__(256) void sm_write_t(const u16* __restrict__ att,
    const int* __restrict__ cnts, const int* __restrict__ gpfx, const int* __restrict__ hloc,
    const float2* __restrict__ bms, u8* __restrict__ p2h, u8* __restrict__ h2p)
{
  __shared__ u8 tile[64][72];
  int b = blockIdx.z, h0 = blockIdx.x*64, p0 = blockIdx.y*64;
  int cp = cnts[b], ch = cnts[128 + b];
  int cp64 = (cp + 63) & ~63, ch64 = (ch + 63) & ~63;
  bool needP = (p0 < cp) && (h0 < ch64);
  bool needH = (h0 < ch) && (p0 < cp64);
  if (!needP && !needH) return;
  float2 ms = bms[b];
  int t = threadIdx.x;
  int rr = t >> 3, cc = (t & 7)*8;
  long base = (long)b*262144;
  long pbase = gpfx[b];
  long hbase = hloc[b];
  #pragma unroll
  for (int pass = 0; pass < 2; ++pass){
    int pr = rr + pass*32;
    uint4 v = *(const uint4*)&att[base + (long)(p0+pr)*512 + h0+cc];
    const u16* vv = (const u16*)&v;
    int pa = (p0 + pr) < cp;
    union { u8 o[8]; uint2 q2; } u;
    #pragma unroll
    for (int j = 0; j < 8; ++j){
      float x = b2f(vv[j]);
      u.o[j] = (pa && (h0+cc+j) < ch) ? (u8)f2e4(__expf(x - ms.x)*ms.y) : (u8)0;
    }
    if (pa) *(uint2*)&p2h[(pbase + p0+pr)*512 + h0+cc] = u.q2;
    #pragma unroll
    for (int j = 0; j < 8; ++j) tile[pr][cc+j] = u.o[j];
  }
  __syncthreads();
  #pragma unroll
  for (int pass = 0; pass < 2; ++pass){
    int hr = rr + pass*32;
    if (h0 + hr < ch){
      union { u8 o[8]; uint2 q2; } u;
      #pragma unroll
      for (int j = 0; j < 8; ++j) u.o[j] = tile[cc+j][hr];
      *(uint2*)&h2p[(hbase + h0+hr)*512 + p0+cc] = u.q2;
    }
  }
}

// ---------------- aggregate FF, parallelized (fp32, 3 stages) ----------------
__global__ __launch_bounds__(256) void ff1_k(const float* __restrict__ agg,
    const float* __restrict__ g0, float* __restrict__ tt)
{
  __shared__ float xs[256];
  int b = blockIdx.y, kc = blockIdx.x, t = threadIdx.x;
  int kbase = kc*256;
  {
    int kk = kbase + t;
    xs[t] = (kk < 512) ? agg[b*512 + kk] : agg[(long)(128 + b)*512 + (kk - 512)];
  }
  __syncthreads();
  float ax = 0.f, ay = 0.f;
  #pragma unroll 4
  for (int k = 0; k < 256; ++k){
    float2 g = *(const float2*)(g0 + (long)(kbase + k)*512 + 2*t);
    ax += xs[k]*g.x; ay += xs[k]*g.y;
  }
  atomicAdd(&tt[b*512 + 2*t],     ax);
  atomicAdd(&tt[b*512 + 2*t + 1], ay);
}

__global__ __launch_bounds__(256) void ff2_k(const float* __restrict__ tt,
    const float* __restrict__ g1, float* __restrict__ x2)
{
  __shared__ float xs[128];
  int b = blockIdx.y, kc = blockIdx.x, t = threadIdx.x;
  int kbase = kc*128;
  if (t < 128) xs[t] = fmaxf(tt[b*512 + kbase + t], 0.f);
  __syncthreads();
  float ax = 0.f, ay = 0.f;
  #pragma unroll 4
  for (int k = 0; k < 128; ++k){
    float2 g = *(const float2*)(g1 + (long)(kbase + k)*512 + 2*t);
    ax += xs[k]*g.x; ay += xs[k]*g.y;
  }
  atomicAdd(&x2[b*512 + 2*t],     ax);
  atomicAdd(&x2[b*512 + 2*t + 1], ay);
}

__global__ __launch_bounds__(64) void score_k(const float* __restrict__ x2,
    const float* __restrict__ sc, float* __restrict__ out)
{
  int b = blockIdx.x, t = threadIdx.x;
  float s0 = 0.f, s1 = 0.f;
  for (int k = t; k < 512; k += 64){
    float v = fmaxf(x2[b*512 + k], 0.f);
    s0 += v*sc[2*k]; s1 += v*sc[2*k + 1];
  }
  #pragma unroll
  for (int d = 1; d < 64; d <<= 1){ s0 += __shfl_xor(s0, d); s1 += __shfl_xor(s1, d); }
  if (t == 0){
    float mm = fmaxf(s0, s1);
    float e0 = __expf(s0 - mm), e1 = __expf(s1 - mm);
    float inv = 1.f / (e0 + e1);
    out[2*b]     = e0*inv;
    out[2*b + 1] = e1*inv;
  }
}

// =============================== launcher ===============================
extern "C" void kernel_launch(void* const* d_in, const int* in_sizes, int n_in,
                              void* d_out, int out_size, void* d_ws, size_t ws_size,
                              hipStream_t stream) {
  const float* premise    = (const float*)d_in[0];
  const float* hypothesis = (const float*)d_in[1];
  const int*   pm         = (const int*)d_in[2];
  const int*   hm         = (const int*)d_in[3];
  const float* w_a0       = (const float*)d_in[4];
  const float* w_a1       = (const float*)d_in[5];
  const float* w_c0       = (const float*)d_in[6];
  const float* w_c1       = (const float*)d_in[7];
  const float* w_g0       = (const float*)d_in[8];
  const float* w_g1       = (const float*)d_in[9];
  const float* w_sc       = (const float*)d_in[10];
  float* out = (float*)d_out;

  const size_t MB = 1ull << 20;
  if (ws_size < 456*MB) return;

  char* ws = (char*)d_ws;
  u8*  embC8 = (u8*)(ws + 0);           // [0,40)    live until l1
  u8*  t08   = (u8*)(ws + 40*MB);       // [40,80)   ff1->ff2 only
  u8*  ap8   = (u8*)(ws + 40*MB);       // [40,60)   packed align_p (t08 dead)
  u8*  ah8   = (u8*)(ws + 60*MB);       // [60,80)   packed align_h
  u8*  proj8 = (u8*)(ws + 80*MB);       // [80,120)  ff2->att (fp8)
  u8*  cmp8  = (u8*)(ws + 80*MB);       // [80,120)  l1->l2 (proj8 dead)
  u8*  pT8   = (u8*)(ws + 160*MB);      // [160,193) p_embT per-batch fp8
  u8*  hT8   = (u8*)(ws + 200*MB);      // [200,233) h_embT per-batch fp8
  u16* att_b = (u16*)(ws + 288*MB);     // [288,352) att->sm_write_t (bf16, L3-resident)
  u8*  p2h8  = (u8*)(ws + 352*MB);      // [352,372) packed fp8
  u8*  h2p8  = (u8*)(ws + 372*MB);      // [372,392) packed fp8
  u8*  wt_a0 = (u8*)(ws + 432*MB);
  u8*  wt_a1 = (u8*)(ws + 432*MB + 256*1024);
  u8*  wt_c1 = (u8*)(ws + 432*MB + 512*1024);
  u8*  wt_c0 = (u8*)(ws + 433*MB);      // [512][1024] fp8 (512 KB)
  float* agg = (float*)(ws + 434*MB);   // [256][512]
  float* tt  = (float*)(ws + 434*MB + 512*1024);
  float* x2  = (float*)(ws + 434*MB + 768*1024);
  int*   pfx = (int*)(ws + 435*MB);
  int* rowMap= (int*)(ws + 436*MB);
  int*  gpfx = (int*)(ws + 437*MB);
  int*  hloc = (int*)(ws + 437*MB + 4096);
  int*  cnts = (int*)(ws + 437*MB + 8192);
  float2* part = (float2*)(ws + 437*MB + 12288);   // 128*16 float2
  float2* bms  = (float2*)(ws + 437*MB + 32768);

  // 1. counts + prefixes, packed fp8 compaction + rowMap
  cnt_scan<<<256, 256, 0, stream>>>(pm, hm, pfx, cnts);
  gscan_k<<<1, 256, 0, stream>>>(cnts, gpfx, hloc);
  compact_copy<<<1024, 256, 0, stream>>>(premise, hypothesis, pm, hm, pfx, gpfx, embC8, rowMap);

  // 2. weight transposes (fp8) + f32 scratch clears
  wtrans3_k<<<dim3(16,16,3), 256, 0, stream>>>(w_a0, w_a1, w_c1, wt_a0, wt_a1, wt_c1);
  wtrans_k<<<dim3(16,32), 256, 0, stream>>>(w_c0, wt_c0, 1024, 512);
  hipMemsetAsync(agg, 0, 256*512*sizeof(float), stream);
  hipMemsetAsync(tt,  0, 128*512*sizeof(float), stream);
  hipMemsetAsync(x2,  0, 128*512*sizeof(float), stream);

  // 3. attend FF on packed M (fp8, 128x128): ff1 -> t08, ff2 -> proj8 (fp8)
  gemm_p8<0,false><<<2112, 256, 0, stream>>>(embC8, nullptr, nullptr, wt_a0, t08, nullptr, gpfx, nullptr, 512, 264);
  gemm_p8<0,false><<<2112, 256, 0, stream>>>(t08, nullptr, nullptr, wt_a1, proj8, nullptr, gpfx, nullptr, 512, 264);

  // 4. per-side fp8 transposes from packed embC (zero-pad to roundup64)
  btrans2<<<dim3(8,8,256), 256, 0, stream>>>(embC8, gpfx, cnts, pT8, hT8);

  // 5. att = projP @ projH^T (fp8, 128x128) + fused masked softmax partials
  gemm_t8<<<2048, 256, 0, stream>>>(proj8, att_b, cnts, gpfx, part);

  // 6. softmax merge + fused fp8 write packed p2h / h2p
  sm_merge<<<1, 128, 0, stream>>>(part, bms);
  sm_write_t<<<dim3(8,8,128), 256, 0, stream>>>(att_b, cnts, gpfx, hloc, bms, p2h8, h2p8);

  // 7. both alignments in ONE fp8 dispatch (128x128)
  gemm_a8<<<4096, 256, 0, stream>>>(p2h8, h2p8, pT8, hT8, ap8, ah8, cnts, gpfx, hloc);

  // 8. compare l1 (fp8, K=1024 split concat) -> fp8 cmp_t
  gemm_p8<0,true><<<2112, 256, 0, stream>>>(embC8, ap8, ah8, wt_c0, cmp8, nullptr, gpfx, nullptr, 1024, 264);

  // 9. compare l2 (fp8) + relu + side-keyed column-sum into agg
  gemm_p8<2,false><<<2112, 256, 0, stream>>>(cmp8, nullptr, nullptr, wt_c1, nullptr, agg, gpfx, rowMap, 512, 264);

  // 10. aggregate FF (parallel fp32) + scorer + 2-class softmax
  ff1_k<<<dim3(4,128), 256, 0, stream>>>(agg, w_g0, tt);
  ff2_k<<<dim3(4,128), 256, 0, stream>>>(tt, w_g1, x2);
  score_k<<<128, 64, 0, stream>>>(x2, w_sc, out);
}